// Round 9
// baseline (242.893 us; speedup 1.0000x reference)
//
#include <hip/hip_runtime.h>
#include <hip/hip_bf16.h>
#include <cstdint>

typedef __attribute__((ext_vector_type(8))) short short8;
typedef __attribute__((ext_vector_type(16))) float f32x16;

// Problem constants (B, N, D, H) = (256, 100000, 512, 2048)
constexpr int M   = 256;
constexpr int NTB = 100000;
constexpr int D   = 512;
constexpr int H   = 2048;

constexpr int SR   = 64;                        // table rows per strip/block
constexpr int NS64 = (NTB + SR - 1) / SR;       // 1563
constexpr float EPS_MARGIN = 6.0f;              // >= 2*eps of hi-only bf16 dot error

// ---- ws layout (bytes) ----
constexpr size_t WS_CODES_HI = 0;                                    // 256KB frag-ordered bf16
constexpr size_t WS_KEYS     = 262144;                               // [256][NS64] u64 = 3.2MB
constexpr size_t WS_IDX      = WS_KEYS + (size_t)M * NS64 * 8;       // 256 u32
constexpr size_t WS_H1       = WS_IDX + 1024;                        // 256*2048 f32

// bf16 helpers (RNE)
__device__ inline unsigned short f2bf_rne(float x) {
  unsigned u = __float_as_uint(x);
  u += 0x7fffu + ((u >> 16) & 1u);
  return (unsigned short)(u >> 16);
}
__device__ inline unsigned long long packkey(float s, unsigned n) {
  unsigned u = __float_as_uint(s);
  u = (u & 0x80000000u) ? ~u : (u | 0x80000000u);  // order-preserving
  return ((unsigned long long)u << 32) | n;
}
__device__ inline float unpackf(unsigned u) {
  u = (u & 0x80000000u) ? (u & 0x7fffffffu) : ~u;
  return __uint_as_float(u);
}
__device__ inline unsigned long long u64min(unsigned long long a, unsigned long long b) {
  return a < b ? a : b;
}

// ---------------- codes -> frag-ordered bf16 hi ----------------
// element (q, k): g=q>>5, s=k>>4, lane=(q&31)|(((k>>3)&1)<<5), j=k&7
// at chi[((g*32+s)*64+lane)*8 + j]
__global__ __launch_bounds__(256) void convert_codes_kernel(
    const float* __restrict__ codes, unsigned short* __restrict__ chi)
{
  const int i = blockIdx.x * 256 + threadIdx.x;  // 0 .. 256*512-1
  const int q = i >> 9, k = i & 511;
  const int g = q >> 5, s = k >> 4;
  const int lane = (q & 31) | (((k >> 3) & 1) << 5);
  const int j = k & 7;
  chi[((size_t)(g * 32 + s) * 64 + (size_t)lane) * 8 + j] = f2bf_rne(codes[i]);
}

// ---------------- dist: LDS-free, barrier-free, uniform-depth prefetch -----
// Block (4 waves) = one 64-row strip. Wave: 64 rows (2 row-tiles) x 2 query
// groups. A loads HBM -> MFMA-fragment registers (row=lane&31,
// k=sg*16+(lane>>5)*8+j), f32->bf16 + csq in-loop. B from L2-resident chi.
// BOTH A and B refills at depth-4 consume distance (~1024 cyc at 2 waves/SIMD
// x 128 matrix-cyc/step) >= worst-class HBM latency, so in-order vmcnt
// retirement never exposes a stall. No LDS, no __syncthreads anywhere.
__global__ __launch_bounds__(256, 2) void dist_mfma_kernel(
    const float* __restrict__ table,
    const unsigned short* __restrict__ chi,
    unsigned long long* __restrict__ keysT)
{
  const int t    = threadIdx.x;
  const int lane = t & 63;
  const int w    = t >> 6;       // wave 0..3 -> query groups 2w, 2w+1
  const int half = lane >> 5;
  const int r32  = lane & 31;
  const int strip = blockIdx.x;
  const int row_base = strip * SR;

  const int rg0 = min(row_base + r32, NTB - 1);
  const int rg1 = min(row_base + 32 + r32, NTB - 1);
  const float* a0src = table + (size_t)rg0 * D + half * 8;
  const float* a1src = table + (size_t)rg1 * D + half * 8;
  const unsigned short* bbase = chi + (size_t)(2 * w) * 16384 + (size_t)lane * 8;

  f32x16 acc[2][2];   // [rt][gt]
  #pragma unroll
  for (int a = 0; a < 2; ++a)
    #pragma unroll
    for (int b = 0; b < 2; ++b)
      #pragma unroll
      for (int r = 0; r < 16; ++r) acc[a][b][r] = 0.f;

  float4 aq[4][4];   // [slot][rt*2 + p]  A queue, 4 K-steps deep
  short8 bbuf[4][2]; // [slot][gt]        B queue, 4 K-steps deep

  #pragma unroll
  for (int i = 0; i < 4; ++i) {
    aq[i][0] = *(const float4*)(a0src + i * 16);
    aq[i][1] = *(const float4*)(a0src + i * 16 + 4);
    aq[i][2] = *(const float4*)(a1src + i * 16);
    aq[i][3] = *(const float4*)(a1src + i * 16 + 4);
  }
  #pragma unroll
  for (int p = 0; p < 4; ++p) {
    bbuf[p][0] = *(const short8*)(bbase + (size_t)p * 512);
    bbuf[p][1] = *(const short8*)(bbase + 16384 + (size_t)p * 512);
  }

  float csq0 = 0.f, csq1 = 0.f;

  #pragma unroll 4
  for (int sg = 0; sg < 32; ++sg) {
    const int slot = sg & 3;
    short8 aH0, aH1;
    {
      float x0[8] = {aq[slot][0].x, aq[slot][0].y, aq[slot][0].z, aq[slot][0].w,
                     aq[slot][1].x, aq[slot][1].y, aq[slot][1].z, aq[slot][1].w};
      float x1[8] = {aq[slot][2].x, aq[slot][2].y, aq[slot][2].z, aq[slot][2].w,
                     aq[slot][3].x, aq[slot][3].y, aq[slot][3].z, aq[slot][3].w};
      #pragma unroll
      for (int j = 0; j < 8; ++j) {
        csq0 += x0[j] * x0[j];
        csq1 += x1[j] * x1[j];
        aH0[j] = (short)f2bf_rne(x0[j]);
        aH1[j] = (short)f2bf_rne(x1[j]);
      }
    }
    if (sg + 4 < 32) {  // A refill, 4 steps ahead
      aq[slot][0] = *(const float4*)(a0src + (sg + 4) * 16);
      aq[slot][1] = *(const float4*)(a0src + (sg + 4) * 16 + 4);
      aq[slot][2] = *(const float4*)(a1src + (sg + 4) * 16);
      aq[slot][3] = *(const float4*)(a1src + (sg + 4) * 16 + 4);
    }
    acc[0][0] = __builtin_amdgcn_mfma_f32_32x32x16_bf16(aH0, bbuf[slot][0], acc[0][0], 0, 0, 0);
    acc[0][1] = __builtin_amdgcn_mfma_f32_32x32x16_bf16(aH0, bbuf[slot][1], acc[0][1], 0, 0, 0);
    acc[1][0] = __builtin_amdgcn_mfma_f32_32x32x16_bf16(aH1, bbuf[slot][0], acc[1][0], 0, 0, 0);
    acc[1][1] = __builtin_amdgcn_mfma_f32_32x32x16_bf16(aH1, bbuf[slot][1], acc[1][1], 0, 0, 0);
    if (sg + 4 < 32) {  // B refill, 4 steps ahead (after MFMA: WAR keeps order)
      bbuf[slot][0] = *(const short8*)(bbase + (size_t)(sg + 4) * 512);
      bbuf[slot][1] = *(const short8*)(bbase + 16384 + (size_t)(sg + 4) * 512);
    }
  }

  // exact f32 csq per row: k-halves live in lane and lane^32
  csq0 += __shfl_xor(csq0, 32);
  csq1 += __shfl_xor(csq1, 32);

  // per-query argmin of score = csq - 2*dot (x_sq const per query; sqrt monotone)
  #pragma unroll
  for (int gt = 0; gt < 2; ++gt) {
    unsigned long long best = ~0ull;
    #pragma unroll
    for (int rt = 0; rt < 2; ++rt) {
      #pragma unroll
      for (int r = 0; r < 16; ++r) {
        const int rl = rt * 32 + (r & 3) + 8 * (r >> 2) + 4 * half;
        const float csq = __shfl(rt ? csq1 : csq0, rl & 31);
        const int rg = min(row_base + rl, NTB - 1);
        const float sc = csq - 2.f * acc[rt][gt][r];
        best = u64min(best, packkey(sc, (unsigned)rg));
      }
    }
    best = u64min(best, __shfl_xor(best, 32));
    if (half == 0) {
      const int q = (2 * w + gt) * 32 + r32;
      keysT[(size_t)q * NS64 + strip] = best;
    }
  }
}

// ---------------- merge (coalesced per-q row) + flagged-strip exact rescore --
// Exactness: true-NN n* has approx(n*) <= best_approx + 2*eps, so its strip's
// min <= best+M (M >= 2*eps) -> strip flagged -> all 64 rows rescored in f32.
__global__ __launch_bounds__(256) void merge_rescore_kernel(
    const unsigned long long* __restrict__ keysT,
    const float* __restrict__ codes, const float* __restrict__ table,
    unsigned* __restrict__ out_idx)
{
  constexpr int FLMAX = 32;
  __shared__ unsigned long long krow[NS64];
  __shared__ float xs[D];
  __shared__ unsigned long long wmin[4];
  __shared__ int flags[FLMAX];
  __shared__ int nf;
  __shared__ float rv[4];
  __shared__ int   ri[4];

  const int q = blockIdx.x, t = threadIdx.x;
  const int lane = t & 63, w = t >> 6;

  if (t == 0) nf = 0;
  for (int i = t; i < NS64; i += 256) krow[i] = keysT[(size_t)q * NS64 + i];
  for (int d = t; d < D; d += 256) xs[d] = codes[(size_t)q * D + d];
  __syncthreads();

  unsigned long long lb = ~0ull;
  for (int i = t; i < NS64; i += 256) lb = u64min(lb, krow[i]);
  #pragma unroll
  for (int off = 1; off < 64; off <<= 1) lb = u64min(lb, __shfl_xor(lb, off));
  if (lane == 0) wmin[w] = lb;
  __syncthreads();
  const unsigned long long bk =
      u64min(u64min(wmin[0], wmin[1]), u64min(wmin[2], wmin[3]));
  const float thr = unpackf((unsigned)(bk >> 32)) + EPS_MARGIN;

  for (int i = t; i < NS64; i += 256) {
    if (unpackf((unsigned)(krow[i] >> 32)) <= thr) {
      int p = atomicAdd(&nf, 1);
      if (p < FLMAX) flags[p] = i;
    }
  }
  __syncthreads();
  const int nfc = min(nf, FLMAX);

  // exact rescore of all rows of flagged strips; wave w owns rows w*16..+15
  float bv = INFINITY;
  int   bi = 0x7fffffff;
  for (int f = 0; f < nfc; ++f) {
    const int sbase = flags[f] * SR;
    for (int rr = 0; rr < 16; ++rr) {
      const int rg = min(sbase + w * 16 + rr, NTB - 1);
      const float* crow = table + (size_t)rg * D + lane * 8;
      float4 c0 = *(const float4*)(crow);
      float4 c1 = *(const float4*)(crow + 4);
      float4 x0 = *(const float4*)(&xs[lane * 8]);
      float4 x1 = *(const float4*)(&xs[lane * 8 + 4]);
      float p = c0.x*c0.x - 2.f*x0.x*c0.x + c0.y*c0.y - 2.f*x0.y*c0.y
              + c0.z*c0.z - 2.f*x0.z*c0.z + c0.w*c0.w - 2.f*x0.w*c0.w
              + c1.x*c1.x - 2.f*x1.x*c1.x + c1.y*c1.y - 2.f*x1.y*c1.y
              + c1.z*c1.z - 2.f*x1.z*c1.z + c1.w*c1.w - 2.f*x1.w*c1.w;
      #pragma unroll
      for (int off = 1; off < 64; off <<= 1) p += __shfl_xor(p, off);
      if (p < bv || (p == bv && rg < bi)) { bv = p; bi = rg; }
    }
  }
  if (lane == 0) { rv[w] = bv; ri[w] = bi; }
  __syncthreads();
  if (t == 0) {
    float fv = rv[0]; int fi = ri[0];
    #pragma unroll
    for (int i = 1; i < 4; ++i)
      if (rv[i] < fv || (rv[i] == fv && ri[i] < fi)) { fv = rv[i]; fi = ri[i]; }
    out_idx[q] = (unsigned)fi;
  }
}

// ---------------- Kernel B1: h1 = relu(gather(table, idx) @ w1 + b1) --------
constexpr int BM2 = 64, BN2 = 64, BK2 = 16;

__global__ __launch_bounds__(256) void mlp1_kernel(
    const unsigned* __restrict__ final_idx,
    const float* __restrict__ table,
    const float* __restrict__ w1, const float* __restrict__ b1,
    float* __restrict__ h1)
{
  __shared__ float As[2][BK2][BM2];
  __shared__ float Bs[2][BK2][BN2];
  __shared__ unsigned idx_s[BM2];

  const int t  = threadIdx.x;
  const int tx = t & 15, ty = t >> 4;
  const int h0 = blockIdx.x * BN2;
  const int m0 = blockIdx.y * BM2;

  if (t < BM2) idx_s[t] = final_idx[m0 + t];
  __syncthreads();

  const int mr = t >> 2, c4 = (t & 3) * 4;
  const int dd = t >> 4, cb = (t & 15) * 4;
  const float* arow = table + (size_t)idx_s[mr] * D + c4;
  const float* brow = w1 + (size_t)dd * H + h0 + cb;

  float acc[4][4] = {{0.f}};

  float4 av = *(const float4*)(arow);
  float4 bv = *(const float4*)(brow);
  {
    float a[4] = {av.x, av.y, av.z, av.w};
    #pragma unroll
    for (int j = 0; j < 4; ++j) As[0][c4 + j][mr] = a[j];
    *(float4*)&Bs[0][dd][cb] = bv;
  }
  __syncthreads();

  for (int kt = 0; kt < D / BK2; ++kt) {
    const int cur = kt & 1;
    if (kt < D / BK2 - 1) {
      av = *(const float4*)(arow + (kt + 1) * BK2);
      bv = *(const float4*)(brow + (size_t)(kt + 1) * BK2 * H);
    }
    #pragma unroll
    for (int kk = 0; kk < BK2; ++kk) {
      float4 a4 = *(const float4*)&As[cur][kk][ty * 4];
      float4 b4 = *(const float4*)&Bs[cur][kk][tx * 4];
      float a[4] = {a4.x,a4.y,a4.z,a4.w}, b[4] = {b4.x,b4.y,b4.z,b4.w};
      #pragma unroll
      for (int i = 0; i < 4; ++i)
        #pragma unroll
        for (int j = 0; j < 4; ++j) acc[i][j] += a[i] * b[j];
    }
    if (kt < D / BK2 - 1) {
      float a[4] = {av.x, av.y, av.z, av.w};
      #pragma unroll
      for (int j = 0; j < 4; ++j) As[cur ^ 1][c4 + j][mr] = a[j];
      *(float4*)&Bs[cur ^ 1][dd][cb] = bv;
    }
    __syncthreads();
  }

  #pragma unroll
  for (int i = 0; i < 4; ++i) {
    const int m = m0 + ty * 4 + i;
    float v0 = acc[i][0] + b1[h0 + tx * 4 + 0];
    float v1 = acc[i][1] + b1[h0 + tx * 4 + 1];
    float v2 = acc[i][2] + b1[h0 + tx * 4 + 2];
    float v3 = acc[i][3] + b1[h0 + tx * 4 + 3];
    float4 o;
    o.x = v0 > 0.f ? v0 : 0.f;
    o.y = v1 > 0.f ? v1 : 0.f;
    o.z = v2 > 0.f ? v2 : 0.f;
    o.w = v3 > 0.f ? v3 : 0.f;
    *(float4*)(h1 + (size_t)m * H + h0 + tx * 4) = o;
  }
}

// ---------------- init d_out with biases (clears 0xAA poison) ----------
__global__ void init_out_kernel(const float* __restrict__ b2u,
                                const float* __restrict__ b2s,
                                float* __restrict__ out)
{
  const int i = blockIdx.x * blockDim.x + threadIdx.x;
  if (i < M * D) out[i] = b2u[i & (D - 1)];
  else           out[i] = b2s[i & (D - 1)];
}

// ---------------- Kernel B2: [mu|logstd] += h1 @ [w2u|w2s]  (split-K=4) ----
constexpr int KSPLIT = 4;

__global__ __launch_bounds__(256) void mlp2_kernel(
    const float* __restrict__ h1,
    const float* __restrict__ w2u, const float* __restrict__ w2s,
    float* __restrict__ out)
{
  __shared__ float As[2][BK2][BM2];
  __shared__ float Bs[2][BK2][BN2];

  const int t  = threadIdx.x;
  const int tx = t & 15, ty = t >> 4;
  const int n0 = blockIdx.x * BN2;           // over [w2u|w2s] concat (2*D wide)
  const int m0 = blockIdx.y * BM2;
  const int k0 = blockIdx.z * (H / KSPLIT);  // 512-wide K chunk

  const float* Wn = (n0 < D) ? w2u : w2s;
  const int col0 = n0 & (D - 1);

  const int mr = t >> 2, c4 = (t & 3) * 4;
  const int dd = t >> 4, cb = (t & 15) * 4;
  const float* arow = h1 + (size_t)(m0 + mr) * H + k0 + c4;
  const float* brow = Wn + (size_t)(k0 + dd) * D + col0 + cb;

  float acc[4][4] = {{0.f}};
  constexpr int NITER = (H / KSPLIT) / BK2;  // 32

  float4 av = *(const float4*)(arow);
  float4 bv = *(const float4*)(brow);
  {
    float a[4] = {av.x, av.y, av.z, av.w};
    #pragma unroll
    for (int j = 0; j < 4; ++j) As[0][c4 + j][mr] = a[j];
    *(float4*)&Bs[0][dd][cb] = bv;
  }
  __syncthreads();

  for (int kt = 0; kt < NITER; ++kt) {
    const int cur = kt & 1;
    if (kt < NITER - 1) {
      av = *(const float4*)(arow + (kt + 1) * BK2);
      bv = *(const float4*)(brow + (size_t)(kt + 1) * BK2 * D);
    }
    #pragma unroll
    for (int kk = 0; kk < BK2; ++kk) {
      float4 a4 = *(const float4*)&As[cur][kk][ty * 4];
      float4 b4 = *(const float4*)&Bs[cur][kk][tx * 4];
      float a[4] = {a4.x,a4.y,a4.z,a4.w}, b[4] = {b4.x,b4.y,b4.z,b4.w};
      #pragma unroll
      for (int i = 0; i < 4; ++i)
        #pragma unroll
        for (int j = 0; j < 4; ++j) acc[i][j] += a[i] * b[j];
    }
    if (kt < NITER - 1) {
      float a[4] = {av.x, av.y, av.z, av.w};
      #pragma unroll
      for (int j = 0; j < 4; ++j) As[cur ^ 1][c4 + j][mr] = a[j];
      *(float4*)&Bs[cur ^ 1][dd][cb] = bv;
    }
    __syncthreads();
  }

  #pragma unroll
  for (int i = 0; i < 4; ++i) {
    const int m = m0 + ty * 4 + i;
    const int c = col0 + tx * 4;
    float* dst = (n0 < D) ? (out + (size_t)m * D + c)
                          : (out + (size_t)(M * D) + (size_t)m * D + c);
    #pragma unroll
    for (int j = 0; j < 4; ++j) atomicAdd(dst + j, acc[i][j]);
  }
}

extern "C" void kernel_launch(void* const* d_in, const int* in_sizes, int n_in,
                              void* d_out, int out_size, void* d_ws, size_t ws_size,
                              hipStream_t stream)
{
  const float* codes = (const float*)d_in[0];
  const float* table = (const float*)d_in[1];
  const float* w1    = (const float*)d_in[2];
  const float* b1    = (const float*)d_in[3];
  const float* w2u   = (const float*)d_in[4];
  const float* b2u   = (const float*)d_in[5];
  const float* w2s   = (const float*)d_in[6];
  const float* b2s   = (const float*)d_in[7];
  float* out = (float*)d_out;

  unsigned short* chi = (unsigned short*)((char*)d_ws + WS_CODES_HI);
  unsigned long long* keysT = (unsigned long long*)((char*)d_ws + WS_KEYS);
  unsigned* final_idx = (unsigned*)((char*)d_ws + WS_IDX);
  float* h1 = (float*)((char*)d_ws + WS_H1);

  convert_codes_kernel<<<(M * D) / 256, 256, 0, stream>>>(codes, chi);

  dist_mfma_kernel<<<NS64, 256, 0, stream>>>(table, chi, keysT);

  merge_rescore_kernel<<<M, 256, 0, stream>>>(keysT, codes, table, final_idx);

  dim3 gB1(H / BN2, M / BM2);
  mlp1_kernel<<<gB1, 256, 0, stream>>>(final_idx, table, w1, b1, h1);

  init_out_kernel<<<(2 * M * D) / 256, 256, 0, stream>>>(b2u, b2s, out);

  dim3 gB2((2 * D) / BN2, M / BM2, KSPLIT);
  mlp2_kernel<<<gB2, 256, 0, stream>>>(h1, w2u, w2s, out);
}

// Round 10
// 207.011 us; speedup vs baseline: 1.1733x; 1.1733x over previous
//
#include <hip/hip_runtime.h>
#include <hip/hip_bf16.h>
#include <cstdint>

typedef __attribute__((ext_vector_type(8))) short short8;
typedef __attribute__((ext_vector_type(4))) int int4v;
typedef __attribute__((ext_vector_type(16))) float f32x16;

// Problem constants (B, N, D, H) = (256, 100000, 512, 2048)
constexpr int M   = 256;
constexpr int NTB = 100000;
constexpr int D   = 512;
constexpr int H   = 2048;

constexpr int SR   = 64;                        // table rows per strip/block
constexpr int NS64 = (NTB + SR - 1) / SR;       // 1563
constexpr float EPS_MARGIN = 8.0f;              // >= 2*eps of trunc-bf16 dot error

// ---- ws layout (bytes) ----
constexpr size_t WS_CODES_HI = 0;                                    // 256KB frag-ordered bf16
constexpr size_t WS_KEYS     = 262144;                               // [256][NS64] u64 = 3.2MB
constexpr size_t WS_IDX      = WS_KEYS + (size_t)M * NS64 * 8;       // 256 u32
constexpr size_t WS_H1       = WS_IDX + 1024;                        // 256*2048 f32

__device__ inline unsigned short f2bf_rne(float x) {
  unsigned u = __float_as_uint(x);
  u += 0x7fffu + ((u >> 16) & 1u);
  return (unsigned short)(u >> 16);
}
__device__ inline unsigned long long packkey(float s, unsigned n) {
  unsigned u = __float_as_uint(s);
  u = (u & 0x80000000u) ? ~u : (u | 0x80000000u);  // order-preserving
  return ((unsigned long long)u << 32) | n;
}
__device__ inline float unpackf(unsigned u) {
  u = (u & 0x80000000u) ? (u & 0x7fffffffu) : ~u;
  return __uint_as_float(u);
}
__device__ inline unsigned long long u64min(unsigned long long a, unsigned long long b) {
  return a < b ? a : b;
}
// pack two f32 -> (bf16(lo) | bf16(hi)<<16) by truncation (error covered by margin+rescue)
__device__ inline int pack_bf2(float lo, float hi) {
  return (int)__builtin_amdgcn_perm(__float_as_uint(hi), __float_as_uint(lo), 0x07060302u);
}

// ---------------- codes -> frag-ordered bf16 hi (RNE) ----------------
// element (q, k): g=q>>5, s=k>>4, lane=(q&31)|(((k>>3)&1)<<5), j=k&7
__global__ __launch_bounds__(256) void convert_codes_kernel(
    const float* __restrict__ codes, unsigned short* __restrict__ chi)
{
  const int i = blockIdx.x * 256 + threadIdx.x;  // 0 .. 256*512-1
  const int q = i >> 9, k = i & 511;
  const int g = q >> 5, s = k >> 4;
  const int lane = (q & 31) | (((k >> 3) & 1) << 5);
  const int j = k & 7;
  chi[((size_t)(g * 32 + s) * 64 + (size_t)lane) * 8 + j] = f2bf_rne(codes[i]);
}

// ---------------- dist: m97-style GEMM + argmin ----------------
// Block (4 waves) = one 64-row strip x all 256 queries (wave w owns q 64w..64w+63).
// Staging: global_load_lds width=16, f32 table tile [64 rows][32 k] row-major in
// LDS with XOR-swizzled 16B-chunk order (linear LDS dest + inverse-swizzled
// per-lane global source -> coalesced HBM reads, conflict-light ds_reads).
// Double-buffered (2 x 8KB), ONE barrier per kt. Fragments: ds_read_b128 x2
// per (mt) -> v_perm trunc-pack to bf16 + exact f32 csq fma -> 4 MFMAs.
// B operand streams from L2-resident pre-swizzled chi, 1 sg prefetch ahead.
__global__ __launch_bounds__(256) void dist_mfma_kernel(
    const float* __restrict__ table,
    const unsigned short* __restrict__ chi,
    unsigned long long* __restrict__ keysT)
{
  __shared__ float AsF[2][2048];   // [buf][512 slots * 4 f32] = 8KB each

  const int t    = threadIdx.x;
  const int lane = t & 63;
  const int w    = t >> 6;       // wave 0..3 -> query groups 2w, 2w+1
  const int half = lane >> 5;    // k-half of the MFMA fragment
  const int r32  = lane & 31;
  const int strip = blockIdx.x;
  const int row_base = strip * SR;

  // staging source for slot s = i*256 + w*64 + lane:
  //   row = s>>3, stored chunk cb = (s&7) ^ (row&7)  (inverse of read swizzle)
  size_t src_off[2];
  #pragma unroll
  for (int i = 0; i < 2; ++i) {
    const int s = i * 256 + w * 64 + lane;
    const int r = s >> 3;
    const int cb = (s & 7) ^ (r & 7);
    src_off[i] = (size_t)min(row_base + r, NTB - 1) * D + cb * 4;
  }

  const unsigned short* bb0 = chi + (size_t)(2 * w) * 16384 + (size_t)lane * 8;
  const unsigned short* bb1 = bb0 + 16384;

  f32x16 acc[2][2];   // [mt][nt]
  #pragma unroll
  for (int a = 0; a < 2; ++a)
    #pragma unroll
    for (int b = 0; b < 2; ++b)
      #pragma unroll
      for (int r = 0; r < 16; ++r) acc[a][b][r] = 0.f;

  float csq[2] = {0.f, 0.f};

  // prologue: stage kt=0 into buf 0; load B sg=0
  #pragma unroll
  for (int i = 0; i < 2; ++i)
    __builtin_amdgcn_global_load_lds(
        (const unsigned int*)(table + src_off[i]),
        (unsigned int*)&AsF[0][(i * 256 + w * 64) * 4], 16, 0, 0);
  short8 bq0 = *(const short8*)(bb0);
  short8 bq1 = *(const short8*)(bb1);
  __syncthreads();

  for (int kt = 0; kt < 16; ++kt) {
    const int cur = kt & 1;
    if (kt < 15) {  // issue next tile into the other buffer (in flight over compute)
      #pragma unroll
      for (int i = 0; i < 2; ++i)
        __builtin_amdgcn_global_load_lds(
            (const unsigned int*)(table + src_off[i] + (kt + 1) * 32),
            (unsigned int*)&AsF[cur ^ 1][(i * 256 + w * 64) * 4], 16, 0, 0);
    }
    #pragma unroll
    for (int sgr = 0; sgr < 2; ++sgr) {
      const int sg = kt * 2 + sgr;
      short8 nb0, nb1;
      if (sg < 31) {  // B prefetch 1 step ahead (L2-resident)
        nb0 = *(const short8*)(bb0 + (size_t)(sg + 1) * 512);
        nb1 = *(const short8*)(bb1 + (size_t)(sg + 1) * 512);
      }
      short8 aH[2];
      #pragma unroll
      for (int mt = 0; mt < 2; ++mt) {
        const int row = mt * 32 + r32;
        const int cb0 = (sgr * 4 + half * 2 + 0) ^ (row & 7);
        const int cb1 = (sgr * 4 + half * 2 + 1) ^ (row & 7);
        float4 x0 = *(const float4*)&AsF[cur][(row * 8 + cb0) * 4];
        float4 x1 = *(const float4*)&AsF[cur][(row * 8 + cb1) * 4];
        csq[mt] += x0.x*x0.x + x0.y*x0.y + x0.z*x0.z + x0.w*x0.w
                 + x1.x*x1.x + x1.y*x1.y + x1.z*x1.z + x1.w*x1.w;
        int4v p;
        p.x = pack_bf2(x0.x, x0.y);
        p.y = pack_bf2(x0.z, x0.w);
        p.z = pack_bf2(x1.x, x1.y);
        p.w = pack_bf2(x1.z, x1.w);
        aH[mt] = __builtin_bit_cast(short8, p);
      }
      acc[0][0] = __builtin_amdgcn_mfma_f32_32x32x16_bf16(aH[0], bq0, acc[0][0], 0, 0, 0);
      acc[0][1] = __builtin_amdgcn_mfma_f32_32x32x16_bf16(aH[0], bq1, acc[0][1], 0, 0, 0);
      acc[1][0] = __builtin_amdgcn_mfma_f32_32x32x16_bf16(aH[1], bq0, acc[1][0], 0, 0, 0);
      acc[1][1] = __builtin_amdgcn_mfma_f32_32x32x16_bf16(aH[1], bq1, acc[1][1], 0, 0, 0);
      if (sg < 31) { bq0 = nb0; bq1 = nb1; }
    }
    __syncthreads();  // drains next-tile loads; flips buffer
  }

  // csq: lane and lane^32 hold the two k-halves of the same row (row = mt*32 + r32)
  csq[0] += __shfl_xor(csq[0], 32);
  csq[1] += __shfl_xor(csq[1], 32);

  // per-query argmin of score = csq - 2*dot  (x_sq const per q; sqrt monotone)
  #pragma unroll
  for (int nt = 0; nt < 2; ++nt) {
    unsigned long long best = ~0ull;
    #pragma unroll
    for (int mt = 0; mt < 2; ++mt) {
      #pragma unroll
      for (int r = 0; r < 16; ++r) {
        const int rl = mt * 32 + (r & 3) + 8 * (r >> 2) + 4 * half;
        const float cs = __shfl(csq[mt], rl & 31);
        const int rg = min(row_base + rl, NTB - 1);
        const float sc = cs - 2.f * acc[mt][nt][r];
        best = u64min(best, packkey(sc, (unsigned)rg));
      }
    }
    best = u64min(best, __shfl_xor(best, 32));
    if (half == 0) {
      const int q = w * 64 + nt * 32 + r32;
      keysT[(size_t)q * NS64 + strip] = best;
    }
  }
}

// ---------------- merge (coalesced per-q row) + flagged-strip exact rescore --
// Exactness: true-NN n* has approx(n*) <= best_approx + 2*eps, so its strip's
// min <= best+MARGIN (MARGIN >= 2*eps) -> strip flagged -> all 64 rows rescored f32.
__global__ __launch_bounds__(256) void merge_rescore_kernel(
    const unsigned long long* __restrict__ keysT,
    const float* __restrict__ codes, const float* __restrict__ table,
    unsigned* __restrict__ out_idx)
{
  constexpr int FLMAX = 32;
  __shared__ unsigned long long krow[NS64];
  __shared__ float xs[D];
  __shared__ unsigned long long wmin[4];
  __shared__ int flags[FLMAX];
  __shared__ int nf;
  __shared__ float rv[4];
  __shared__ int   ri[4];

  const int q = blockIdx.x, t = threadIdx.x;
  const int lane = t & 63, w = t >> 6;

  if (t == 0) nf = 0;
  for (int i = t; i < NS64; i += 256) krow[i] = keysT[(size_t)q * NS64 + i];
  for (int d = t; d < D; d += 256) xs[d] = codes[(size_t)q * D + d];
  __syncthreads();

  unsigned long long lb = ~0ull;
  for (int i = t; i < NS64; i += 256) lb = u64min(lb, krow[i]);
  #pragma unroll
  for (int off = 1; off < 64; off <<= 1) lb = u64min(lb, __shfl_xor(lb, off));
  if (lane == 0) wmin[w] = lb;
  __syncthreads();
  const unsigned long long bk =
      u64min(u64min(wmin[0], wmin[1]), u64min(wmin[2], wmin[3]));
  const float thr = unpackf((unsigned)(bk >> 32)) + EPS_MARGIN;

  for (int i = t; i < NS64; i += 256) {
    if (unpackf((unsigned)(krow[i] >> 32)) <= thr) {
      int p = atomicAdd(&nf, 1);
      if (p < FLMAX) flags[p] = i;
    }
  }
  __syncthreads();
  const int nfc = min(nf, FLMAX);

  // exact f32 rescore of all rows of flagged strips; wave w owns rows w*16..+15
  float bv = INFINITY;
  int   bi = 0x7fffffff;
  for (int f = 0; f < nfc; ++f) {
    const int sbase = flags[f] * SR;
    for (int rr = 0; rr < 16; ++rr) {
      const int rg = min(sbase + w * 16 + rr, NTB - 1);
      const float* crow = table + (size_t)rg * D + lane * 8;
      float4 c0 = *(const float4*)(crow);
      float4 c1 = *(const float4*)(crow + 4);
      float4 x0 = *(const float4*)(&xs[lane * 8]);
      float4 x1 = *(const float4*)(&xs[lane * 8 + 4]);
      float p = c0.x*c0.x - 2.f*x0.x*c0.x + c0.y*c0.y - 2.f*x0.y*c0.y
              + c0.z*c0.z - 2.f*x0.z*c0.z + c0.w*c0.w - 2.f*x0.w*c0.w
              + c1.x*c1.x - 2.f*x1.x*c1.x + c1.y*c1.y - 2.f*x1.y*c1.y
              + c1.z*c1.z - 2.f*x1.z*c1.z + c1.w*c1.w - 2.f*x1.w*c1.w;
      #pragma unroll
      for (int off = 1; off < 64; off <<= 1) p += __shfl_xor(p, off);
      if (p < bv || (p == bv && rg < bi)) { bv = p; bi = rg; }
    }
  }
  if (lane == 0) { rv[w] = bv; ri[w] = bi; }
  __syncthreads();
  if (t == 0) {
    float fv = rv[0]; int fi = ri[0];
    #pragma unroll
    for (int i = 1; i < 4; ++i)
      if (rv[i] < fv || (rv[i] == fv && ri[i] < fi)) { fv = rv[i]; fi = ri[i]; }
    out_idx[q] = (unsigned)fi;
  }
}

// ---------------- Kernel B1: h1 = relu(gather(table, idx) @ w1 + b1) --------
constexpr int BM2 = 64, BN2 = 64, BK2 = 16;

__global__ __launch_bounds__(256) void mlp1_kernel(
    const unsigned* __restrict__ final_idx,
    const float* __restrict__ table,
    const float* __restrict__ w1, const float* __restrict__ b1,
    float* __restrict__ h1)
{
  __shared__ float As[2][BK2][BM2];
  __shared__ float Bs[2][BK2][BN2];
  __shared__ unsigned idx_s[BM2];

  const int t  = threadIdx.x;
  const int tx = t & 15, ty = t >> 4;
  const int h0 = blockIdx.x * BN2;
  const int m0 = blockIdx.y * BM2;

  if (t < BM2) idx_s[t] = final_idx[m0 + t];
  __syncthreads();

  const int mr = t >> 2, c4 = (t & 3) * 4;
  const int dd = t >> 4, cb = (t & 15) * 4;
  const float* arow = table + (size_t)idx_s[mr] * D + c4;
  const float* brow = w1 + (size_t)dd * H + h0 + cb;

  float acc[4][4] = {{0.f}};

  float4 av = *(const float4*)(arow);
  float4 bv = *(const float4*)(brow);
  {
    float a[4] = {av.x, av.y, av.z, av.w};
    #pragma unroll
    for (int j = 0; j < 4; ++j) As[0][c4 + j][mr] = a[j];
    *(float4*)&Bs[0][dd][cb] = bv;
  }
  __syncthreads();

  for (int kt = 0; kt < D / BK2; ++kt) {
    const int cur = kt & 1;
    if (kt < D / BK2 - 1) {
      av = *(const float4*)(arow + (kt + 1) * BK2);
      bv = *(const float4*)(brow + (size_t)(kt + 1) * BK2 * H);
    }
    #pragma unroll
    for (int kk = 0; kk < BK2; ++kk) {
      float4 a4 = *(const float4*)&As[cur][kk][ty * 4];
      float4 b4 = *(const float4*)&Bs[cur][kk][tx * 4];
      float a[4] = {a4.x,a4.y,a4.z,a4.w}, b[4] = {b4.x,b4.y,b4.z,b4.w};
      #pragma unroll
      for (int i = 0; i < 4; ++i)
        #pragma unroll
        for (int j = 0; j < 4; ++j) acc[i][j] += a[i] * b[j];
    }
    if (kt < D / BK2 - 1) {
      float a[4] = {av.x, av.y, av.z, av.w};
      #pragma unroll
      for (int j = 0; j < 4; ++j) As[cur ^ 1][c4 + j][mr] = a[j];
      *(float4*)&Bs[cur ^ 1][dd][cb] = bv;
    }
    __syncthreads();
  }

  #pragma unroll
  for (int i = 0; i < 4; ++i) {
    const int m = m0 + ty * 4 + i;
    float v0 = acc[i][0] + b1[h0 + tx * 4 + 0];
    float v1 = acc[i][1] + b1[h0 + tx * 4 + 1];
    float v2 = acc[i][2] + b1[h0 + tx * 4 + 2];
    float v3 = acc[i][3] + b1[h0 + tx * 4 + 3];
    float4 o;
    o.x = v0 > 0.f ? v0 : 0.f;
    o.y = v1 > 0.f ? v1 : 0.f;
    o.z = v2 > 0.f ? v2 : 0.f;
    o.w = v3 > 0.f ? v3 : 0.f;
    *(float4*)(h1 + (size_t)m * H + h0 + tx * 4) = o;
  }
}

// ---------------- init d_out with biases (clears 0xAA poison) ----------
__global__ void init_out_kernel(const float* __restrict__ b2u,
                                const float* __restrict__ b2s,
                                float* __restrict__ out)
{
  const int i = blockIdx.x * blockDim.x + threadIdx.x;
  if (i < M * D) out[i] = b2u[i & (D - 1)];
  else           out[i] = b2s[i & (D - 1)];
}

// ---------------- Kernel B2: [mu|logstd] += h1 @ [w2u|w2s]  (split-K=4) ----
constexpr int KSPLIT = 4;

__global__ __launch_bounds__(256) void mlp2_kernel(
    const float* __restrict__ h1,
    const float* __restrict__ w2u, const float* __restrict__ w2s,
    float* __restrict__ out)
{
  __shared__ float As[2][BK2][BM2];
  __shared__ float Bs[2][BK2][BN2];

  const int t  = threadIdx.x;
  const int tx = t & 15, ty = t >> 4;
  const int n0 = blockIdx.x * BN2;           // over [w2u|w2s] concat (2*D wide)
  const int m0 = blockIdx.y * BM2;
  const int k0 = blockIdx.z * (H / KSPLIT);  // 512-wide K chunk

  const float* Wn = (n0 < D) ? w2u : w2s;
  const int col0 = n0 & (D - 1);

  const int mr = t >> 2, c4 = (t & 3) * 4;
  const int dd = t >> 4, cb = (t & 15) * 4;
  const float* arow = h1 + (size_t)(m0 + mr) * H + k0 + c4;
  const float* brow = Wn + (size_t)(k0 + dd) * D + col0 + cb;

  float acc[4][4] = {{0.f}};
  constexpr int NITER = (H / KSPLIT) / BK2;  // 32

  float4 av = *(const float4*)(arow);
  float4 bv = *(const float4*)(brow);
  {
    float a[4] = {av.x, av.y, av.z, av.w};
    #pragma unroll
    for (int j = 0; j < 4; ++j) As[0][c4 + j][mr] = a[j];
    *(float4*)&Bs[0][dd][cb] = bv;
  }
  __syncthreads();

  for (int kt = 0; kt < NITER; ++kt) {
    const int cur = kt & 1;
    if (kt < NITER - 1) {
      av = *(const float4*)(arow + (kt + 1) * BK2);
      bv = *(const float4*)(brow + (size_t)(kt + 1) * BK2 * D);
    }
    #pragma unroll
    for (int kk = 0; kk < BK2; ++kk) {
      float4 a4 = *(const float4*)&As[cur][kk][ty * 4];
      float4 b4 = *(const float4*)&Bs[cur][kk][tx * 4];
      float a[4] = {a4.x,a4.y,a4.z,a4.w}, b[4] = {b4.x,b4.y,b4.z,b4.w};
      #pragma unroll
      for (int i = 0; i < 4; ++i)
        #pragma unroll
        for (int j = 0; j < 4; ++j) acc[i][j] += a[i] * b[j];
    }
    if (kt < NITER - 1) {
      float a[4] = {av.x, av.y, av.z, av.w};
      #pragma unroll
      for (int j = 0; j < 4; ++j) As[cur ^ 1][c4 + j][mr] = a[j];
      *(float4*)&Bs[cur ^ 1][dd][cb] = bv;
    }
    __syncthreads();
  }

  #pragma unroll
  for (int i = 0; i < 4; ++i) {
    const int m = m0 + ty * 4 + i;
    const int c = col0 + tx * 4;
    float* dst = (n0 < D) ? (out + (size_t)m * D + c)
                          : (out + (size_t)(M * D) + (size_t)m * D + c);
    #pragma unroll
    for (int j = 0; j < 4; ++j) atomicAdd(dst + j, acc[i][j]);
  }
}

extern "C" void kernel_launch(void* const* d_in, const int* in_sizes, int n_in,
                              void* d_out, int out_size, void* d_ws, size_t ws_size,
                              hipStream_t stream)
{
  const float* codes = (const float*)d_in[0];
  const float* table = (const float*)d_in[1];
  const float* w1    = (const float*)d_in[2];
  const float* b1    = (const float*)d_in[3];
  const float* w2u   = (const float*)d_in[4];
  const float* b2u   = (const float*)d_in[5];
  const float* w2s   = (const float*)d_in[6];
  const float* b2s   = (const float*)d_in[7];
  float* out = (float*)d_out;

  unsigned short* chi = (unsigned short*)((char*)d_ws + WS_CODES_HI);
  unsigned long long* keysT = (unsigned long long*)((char*)d_ws + WS_KEYS);
  unsigned* final_idx = (unsigned*)((char*)d_ws + WS_IDX);
  float* h1 = (float*)((char*)d_ws + WS_H1);

  convert_codes_kernel<<<(M * D) / 256, 256, 0, stream>>>(codes, chi);

  dist_mfma_kernel<<<NS64, 256, 0, stream>>>(table, chi, keysT);

  merge_rescore_kernel<<<M, 256, 0, stream>>>(keysT, codes, table, final_idx);

  dim3 gB1(H / BN2, M / BM2);
  mlp1_kernel<<<gB1, 256, 0, stream>>>(final_idx, table, w1, b1, h1);

  init_out_kernel<<<(2 * M * D) / 256, 256, 0, stream>>>(b2u, b2s, out);

  dim3 gB2((2 * D) / BN2, M / BM2, KSPLIT);
  mlp2_kernel<<<gB2, 256, 0, stream>>>(h1, w2u, w2s, out);
}